// Round 1
// baseline (316.954 us; speedup 1.0000x reference)
//
#include <hip/hip_runtime.h>
#include <hip/hip_bf16.h>

#define H_   16
#define NQ_  2048
#define NK_  2048
#define DM_  1024

typedef float f32x4 __attribute__((ext_vector_type(4)));
typedef __bf16 bf16x8 __attribute__((ext_vector_type(8)));
typedef unsigned short u16x8 __attribute__((ext_vector_type(8)));

__device__ __forceinline__ unsigned short f2bf(float x) {
  unsigned int u = __builtin_bit_cast(unsigned int, x);
  unsigned int r = (u + 0x7fffu + ((u >> 16) & 1u)) >> 16;
  return (unsigned short)r;
}
__device__ __forceinline__ float bf2f(unsigned short h) {
  unsigned int u = ((unsigned int)h) << 16;
  return __builtin_bit_cast(float, u);
}

// ---------------- prep: f32 -> bf16 bulk convert (8 elems/thread) ----------------
__global__ __launch_bounds__(256) void cvt_f32_bf16(const float* __restrict__ src,
                                                    unsigned short* __restrict__ dst, int n8) {
  int i = blockIdx.x * 256 + threadIdx.x;
  if (i >= n8) return;
  const float4* s4 = (const float4*)src;
  float4 a = s4[2 * i], b = s4[2 * i + 1];
  u16x8 o;
  o[0] = f2bf(a.x); o[1] = f2bf(a.y); o[2] = f2bf(a.z); o[3] = f2bf(a.w);
  o[4] = f2bf(b.x); o[5] = f2bf(b.y); o[6] = f2bf(b.z); o[7] = f2bf(b.w);
  *((u16x8*)dst + i) = o;
}

// ---------------- prep: transpose 1024x1024 f32 -> bf16 (SPLIT=1: Wo -> [hi,hi,lo] x3K) ----
template <int SPLIT>
__global__ __launch_bounds__(256) void transpose_cvt(const float* __restrict__ src,
                                                     unsigned short* __restrict__ dst) {
  __shared__ float t[64][65];
  const int r0 = blockIdx.x * 64, c0 = blockIdx.y * 64;
  for (int i = threadIdx.x; i < 4096; i += 256) {
    int r = i >> 6, c = i & 63;
    t[r][c] = src[(size_t)(r0 + r) * DM_ + c0 + c];
  }
  __syncthreads();
  for (int i = threadIdx.x; i < 4096; i += 256) {
    int n = i >> 6, k = i & 63;
    float w = t[k][n];
    if (!SPLIT) {
      dst[(size_t)(c0 + n) * DM_ + r0 + k] = f2bf(w);
    } else {
      unsigned short hi = f2bf(w);
      float lo = w - bf2f(hi);
      size_t base = (size_t)(c0 + n) * (3 * DM_) + r0 + k;
      dst[base] = hi;
      dst[base + DM_] = hi;
      dst[base + 2 * DM_] = f2bf(lo);
    }
  }
}

// ---------------- bf16 GEMM, 128x128 tile, BK=32, global_load_lds staging ----------------
// C[m][n] = sum_k A[m][k] * Bt[n][k]  (+ epilogue per MODE)
// MODE 0: Q proj   -> Qp (B,H,NQ,64) bf16, val=(acc+bq[col])*0.125
// MODE 1: K proj   -> Kp (B,H,NK,64) bf16, val=(acc+bk[col])*gate(b,key,col)
// MODE 2: V proj^T (A=WvT, Bt=values_bf) -> VpT (B,H,64,NK) bf16, val=(acc+bv[row])*gate
// MODE 3: out proj -> f32 d_out, val=acc+bo[col]
__device__ __forceinline__ void gll16(const unsigned short* g, unsigned short* l) {
  __builtin_amdgcn_global_load_lds((const __attribute__((address_space(1))) void*)g,
                                   (__attribute__((address_space(3))) void*)l, 16, 0, 0);
}

template <int MODE>
__global__ __launch_bounds__(256) void gemm_bf16(
    const unsigned short* __restrict__ A, const unsigned short* __restrict__ Bt, int K,
    const float* __restrict__ bias, const float* __restrict__ mem,
    const float* __restrict__ Wmm, const float* __restrict__ bmm,
    unsigned short* __restrict__ obf, float* __restrict__ of32) {
  __shared__ unsigned short Al[128 * 32];
  __shared__ unsigned short Bl[128 * 32];
  const int tid = threadIdx.x, lane = tid & 63, w = tid >> 6;
  const int wm = w >> 1, wn = w & 1;
  const int m0 = blockIdx.x * 128, n0 = blockIdx.y * 128;
  const int lrow = lane >> 2, lcol = (lane & 3) * 8;
  const int fr = lane & 15, fk = (lane >> 4) * 8;

  f32x4 acc[4][4] = {};

  const unsigned short* ag0 = A + (size_t)(m0 + w * 32 + lrow) * K + lcol;
  const unsigned short* bg0 = Bt + (size_t)(n0 + w * 32 + lrow) * K + lcol;
  unsigned short* la0 = &Al[(w * 32) * 32];
  unsigned short* la1 = &Al[(w * 32 + 16) * 32];
  unsigned short* lb0 = &Bl[(w * 32) * 32];
  unsigned short* lb1 = &Bl[(w * 32 + 16) * 32];
  const size_t s16K = (size_t)16 * K;

  const int KT = K >> 5;
  for (int kt = 0; kt < KT; ++kt) {
    gll16(ag0, la0); gll16(ag0 + s16K, la1);
    gll16(bg0, lb0); gll16(bg0 + s16K, lb1);
    ag0 += 32; bg0 += 32;
    __syncthreads();
    bf16x8 af[4], bfr[4];
#pragma unroll
    for (int i = 0; i < 4; ++i) af[i] = *(const bf16x8*)&Al[(wm * 64 + i * 16 + fr) * 32 + fk];
#pragma unroll
    for (int j = 0; j < 4; ++j) bfr[j] = *(const bf16x8*)&Bl[(wn * 64 + j * 16 + fr) * 32 + fk];
#pragma unroll
    for (int i = 0; i < 4; ++i)
#pragma unroll
      for (int j = 0; j < 4; ++j)
        acc[i][j] = __builtin_amdgcn_mfma_f32_16x16x32_bf16(af[i], bfr[j], acc[i][j], 0, 0, 0);
    __syncthreads();
  }

#pragma unroll
  for (int i = 0; i < 4; ++i) {
    const int rowb = m0 + wm * 64 + i * 16 + (lane >> 4) * 4;
#pragma unroll
    for (int j = 0; j < 4; ++j) {
      const int col = n0 + wn * 64 + j * 16 + fr;
#pragma unroll
      for (int r = 0; r < 4; ++r) {
        float v = acc[i][j][r];
        int rr = rowb + r;
        if (MODE == 0) {
          int b = rr >> 11, nq = rr & 2047, h = col >> 6, d = col & 63;
          float val = (v + bias[col]) * 0.125f;
          obf[(((size_t)(b * H_ + h)) * NQ_ + nq) * 64 + d] = f2bf(val);
        } else if (MODE == 1) {
          int b = rr >> 11, nk = rr & 2047, h = col >> 6, d = col & 63;
          float gate = mem[b * NK_ + nk] * Wmm[col] + bmm[col];
          float val = (v + bias[col]) * gate;
          obf[(((size_t)(b * H_ + h)) * NK_ + nk) * 64 + d] = f2bf(val);
        } else if (MODE == 2) {
          int b = col >> 11, key = col & 2047, h = rr >> 6, d = rr & 63;
          float gate = mem[b * NK_ + key] * Wmm[rr] + bmm[rr];
          float val = (v + bias[rr]) * gate;
          obf[(((size_t)(b * H_ + h)) * 64 + d) * NK_ + key] = f2bf(val);
        } else {
          of32[(size_t)rr * DM_ + col] = v + bias[col];
        }
      }
    }
  }
}

// ---------------- flash attention: 4 waves, Q-tile 128, KV-tile 64 ----------------
__global__ __launch_bounds__(256) void flash_attn(const unsigned short* __restrict__ Qp,
                                                  const unsigned short* __restrict__ Kp,
                                                  const unsigned short* __restrict__ VpT,
                                                  unsigned short* __restrict__ AO2) {
  __shared__ unsigned short Qs[128][72];
  __shared__ unsigned short Ks[64][72];
  __shared__ unsigned short Vs[64][72];
  __shared__ unsigned short Ps[128][72];

  const int tid = threadIdx.x, lane = tid & 63, w = tid >> 6;
  const int bh = blockIdx.x >> 4;
  const int qt = blockIdx.x & 15;
  const int fr = lane & 15, fk8 = (lane >> 4) * 8;
  const int rbase = (lane >> 4) * 4;
  const int wq = w * 32;

  {
    const unsigned short* qg = Qp + ((size_t)bh * NQ_ + qt * 128) * 64;
    for (int i = tid; i < 1024; i += 256) {
      int r = i >> 3, c = (i & 7) * 8;
      *(u16x8*)&Qs[r][c] = *(const u16x8*)&qg[r * 64 + c];
    }
  }

  f32x4 acc_o[2][4] = {};
  float m_run[2][4], l_run[2][4];
#pragma unroll
  for (int s = 0; s < 2; ++s)
#pragma unroll
    for (int r = 0; r < 4; ++r) { m_run[s][r] = -1e30f; l_run[s][r] = 0.0f; }

  for (int kt = 0; kt < 32; ++kt) {
    __syncthreads();  // prior-tile LDS reads done; Q visible on first iter
    {
      const unsigned short* kg = Kp + ((size_t)bh * NK_ + kt * 64) * 64;
      const unsigned short* vg = VpT + (size_t)bh * 64 * NK_ + kt * 64;
      for (int i = tid; i < 512; i += 256) {
        int r = i >> 3, c = (i & 7) * 8;
        *(u16x8*)&Ks[r][c] = *(const u16x8*)&kg[r * 64 + c];
        *(u16x8*)&Vs[r][c] = *(const u16x8*)&vg[(size_t)r * NK_ + c];
      }
    }
    __syncthreads();

    // S = Q K'^T
    bf16x8 aq[2][2];
#pragma unroll
    for (int s = 0; s < 2; ++s)
#pragma unroll
      for (int ks = 0; ks < 2; ++ks)
        aq[s][ks] = *(const bf16x8*)&Qs[wq + s * 16 + fr][ks * 32 + fk8];

    f32x4 sv[2][4];
#pragma unroll
    for (int kk = 0; kk < 4; ++kk) {
      bf16x8 b0 = *(const bf16x8*)&Ks[kk * 16 + fr][fk8];
      bf16x8 b1 = *(const bf16x8*)&Ks[kk * 16 + fr][32 + fk8];
#pragma unroll
      for (int s = 0; s < 2; ++s) {
        f32x4 z = {0.f, 0.f, 0.f, 0.f};
        z = __builtin_amdgcn_mfma_f32_16x16x32_bf16(aq[s][0], b0, z, 0, 0, 0);
        sv[s][kk] = __builtin_amdgcn_mfma_f32_16x16x32_bf16(aq[s][1], b1, z, 0, 0, 0);
      }
    }

    // online softmax (rows live in 16-lane groups; reduce via shfl_xor 1,2,4,8)
#pragma unroll
    for (int s = 0; s < 2; ++s) {
      float mx[4];
#pragma unroll
      for (int r = 0; r < 4; ++r)
        mx[r] = fmaxf(fmaxf(sv[s][0][r], sv[s][1][r]), fmaxf(sv[s][2][r], sv[s][3][r]));
#pragma unroll
      for (int off = 1; off <= 8; off <<= 1)
#pragma unroll
        for (int r = 0; r < 4; ++r) mx[r] = fmaxf(mx[r], __shfl_xor(mx[r], off));
      float ps[4] = {0.f, 0.f, 0.f, 0.f};
#pragma unroll
      for (int r = 0; r < 4; ++r) {
        float mn = fmaxf(m_run[s][r], mx[r]);
        float sc = __expf(m_run[s][r] - mn);
        m_run[s][r] = mn;
        l_run[s][r] *= sc;
#pragma unroll
        for (int n = 0; n < 4; ++n) acc_o[s][n][r] *= sc;
      }
#pragma unroll
      for (int kk = 0; kk < 4; ++kk)
#pragma unroll
        for (int r = 0; r < 4; ++r) {
          float p = __expf(sv[s][kk][r] - m_run[s][r]);
          ps[r] += p;
          Ps[wq + s * 16 + rbase + r][kk * 16 + fr] = f2bf(p);  // wave-private rows
        }
#pragma unroll
      for (int off = 1; off <= 8; off <<= 1)
#pragma unroll
        for (int r = 0; r < 4; ++r) ps[r] += __shfl_xor(ps[r], off);
#pragma unroll
      for (int r = 0; r < 4; ++r) l_run[s][r] += ps[r];
    }

    // O += P V'  (Ps write->read is same-wave, in-order LDS: no barrier needed)
#pragma unroll
    for (int s = 0; s < 2; ++s)
#pragma unroll
      for (int ks = 0; ks < 2; ++ks) {
        bf16x8 pa = *(const bf16x8*)&Ps[wq + s * 16 + fr][ks * 32 + fk8];
#pragma unroll
        for (int n = 0; n < 4; ++n) {
          bf16x8 vb = *(const bf16x8*)&Vs[n * 16 + fr][ks * 32 + fk8];
          acc_o[s][n] = __builtin_amdgcn_mfma_f32_16x16x32_bf16(pa, vb, acc_o[s][n], 0, 0, 0);
        }
      }
  }

  // epilogue: normalize, split hi/lo, write AO2 (4096 x 3072) = [hi | lo | hi]
  const int b = bh >> 4, h = bh & 15;
#pragma unroll
  for (int s = 0; s < 2; ++s) {
    float linv[4];
#pragma unroll
    for (int r = 0; r < 4; ++r) linv[r] = 1.0f / l_run[s][r];
#pragma unroll
    for (int n = 0; n < 4; ++n)
#pragma unroll
      for (int r = 0; r < 4; ++r) {
        float val = acc_o[s][n][r] * linv[r];
        int qrow = qt * 128 + wq + s * 16 + rbase + r;
        int col = h * 64 + n * 16 + fr;
        size_t base = ((size_t)b * NQ_ + qrow) * 3072;
        unsigned short hi = f2bf(val);
        float lo = val - bf2f(hi);
        AO2[base + col] = hi;
        AO2[base + 1024 + col] = f2bf(lo);
        AO2[base + 2048 + col] = hi;
      }
  }
}

extern "C" void kernel_launch(void* const* d_in, const int* in_sizes, int n_in,
                              void* d_out, int out_size, void* d_ws, size_t ws_size,
                              hipStream_t stream) {
  const float* queries = (const float*)d_in[0];
  const float* keys    = (const float*)d_in[1];
  const float* values  = (const float*)d_in[2];
  const float* memory  = (const float*)d_in[3];
  const float* Wq  = (const float*)d_in[4];
  const float* bq  = (const float*)d_in[5];
  const float* Wk  = (const float*)d_in[6];
  const float* bk  = (const float*)d_in[7];
  const float* Wv  = (const float*)d_in[8];
  const float* bv  = (const float*)d_in[9];
  const float* Wo  = (const float*)d_in[10];
  const float* bo  = (const float*)d_in[11];
  const float* Wmm = (const float*)d_in[12];
  const float* bmm = (const float*)d_in[13];

  char* ws = (char*)d_ws;
  const size_t SZ_X = (size_t)4096 * 1024 * 2;  // 8 MiB per bf16 input copy
  unsigned short* qbf = (unsigned short*)(ws);
  unsigned short* kbf = (unsigned short*)(ws + SZ_X);
  unsigned short* vbf = (unsigned short*)(ws + 2 * SZ_X);
  unsigned short* AO2 = (unsigned short*)(ws);  // 4096x3072, aliases qbf/kbf/vbf (dead by then)
  size_t off = 3 * SZ_X;
  unsigned short* WqT  = (unsigned short*)(ws + off); off += (size_t)1024 * 1024 * 2;
  unsigned short* WkT  = (unsigned short*)(ws + off); off += (size_t)1024 * 1024 * 2;
  unsigned short* WvT  = (unsigned short*)(ws + off); off += (size_t)1024 * 1024 * 2;
  unsigned short* WoT2 = (unsigned short*)(ws + off); off += (size_t)1024 * 3072 * 2;
  unsigned short* Qp   = (unsigned short*)(ws + off); off += SZ_X;
  unsigned short* Kp   = (unsigned short*)(ws + off); off += SZ_X;
  unsigned short* VpT  = (unsigned short*)(ws + off); off += SZ_X;

  const int n8 = 4096 * 1024 / 8;
  cvt_f32_bf16<<<2048, 256, 0, stream>>>(queries, qbf, n8);
  cvt_f32_bf16<<<2048, 256, 0, stream>>>(keys, kbf, n8);
  cvt_f32_bf16<<<2048, 256, 0, stream>>>(values, vbf, n8);
  transpose_cvt<0><<<dim3(16, 16), 256, 0, stream>>>(Wq, WqT);
  transpose_cvt<0><<<dim3(16, 16), 256, 0, stream>>>(Wk, WkT);
  transpose_cvt<0><<<dim3(16, 16), 256, 0, stream>>>(Wv, WvT);
  transpose_cvt<1><<<dim3(16, 16), 256, 0, stream>>>(Wo, WoT2);

  gemm_bf16<0><<<dim3(32, 8), 256, 0, stream>>>(qbf, WqT, 1024, bq, nullptr, nullptr, nullptr, Qp, nullptr);
  gemm_bf16<1><<<dim3(32, 8), 256, 0, stream>>>(kbf, WkT, 1024, bk, memory, Wmm, bmm, Kp, nullptr);
  gemm_bf16<2><<<dim3(8, 32), 256, 0, stream>>>(WvT, vbf, 1024, bv, memory, Wmm, bmm, VpT, nullptr);

  flash_attn<<<512, 256, 0, stream>>>(Qp, Kp, VpT, AO2);

  gemm_bf16<3><<<dim3(32, 8), 256, 0, stream>>>(AO2, WoT2, 3072, bo, nullptr, nullptr, nullptr,
                                                nullptr, (float*)d_out);
}